// Round 7
// baseline (543.254 us; speedup 1.0000x reference)
//
#include <hip/hip_runtime.h>
#include <stdint.h>

#define BB   2
#define SS   2048
#define DD   1024
#define HH   16
#define DKK  64
#define MM   (BB*SS)   // 4096 rows total

typedef __attribute__((ext_vector_type(4))) float f32x4;
typedef __attribute__((ext_vector_type(8))) short s16x8;

#define MFMA_B16(a, b, c) __builtin_amdgcn_mfma_f32_16x16x32_bf16((a), (b), (c), 0, 0, 0)

__device__ __forceinline__ ushort f2bf(float f) {
  uint u = __float_as_uint(f);
  u += 0x7FFFu + ((u >> 16) & 1u);   // round-to-nearest-even
  return (ushort)(u >> 16);
}
__device__ __forceinline__ float bf2f(ushort u) {
  return __uint_as_float((uint)u << 16);
}

// ---------------- fp32 -> bf16 convert (8 elems/thread) ----------------
__global__ void cvt_kernel(const float* __restrict__ src, ushort* __restrict__ dst, int n) {
  int i = (blockIdx.x * 256 + threadIdx.x) * 8;
  if (i >= n) return;
  const float4* s4 = (const float4*)(src + i);
  float4 a = s4[0], b = s4[1];
  union { ushort u[8]; s16x8 v; } r;
  r.u[0] = f2bf(a.x); r.u[1] = f2bf(a.y); r.u[2] = f2bf(a.z); r.u[3] = f2bf(a.w);
  r.u[4] = f2bf(b.x); r.u[5] = f2bf(b.y); r.u[6] = f2bf(b.z); r.u[7] = f2bf(b.w);
  *(s16x8*)(dst + i) = r.v;
}

// ---------------- Y = A @ W^T  (A:[4096,1024] bf16, W:[1024,1024] bf16) ----------------
// mode 0: Q-proj -> [B,H,S,DK] bf16, scaled by 1/8
// mode 1: K-proj -> [B,H,S,DK] bf16
// mode 2: V-proj -> [B,H,DK,S] bf16 (transposed)
// mode 3: O-proj -> [4096,1024] fp32 (d_out)
__global__ __launch_bounds__(256, 2) void proj_gemm(
    const ushort* __restrict__ A, const ushort* __restrict__ W,
    void* __restrict__ outp, int mode)
{
  __shared__ ushort As[128 * 32];
  __shared__ ushort Bs[128 * 32];
  const int tid  = threadIdx.x;
  const int lane = tid & 63, wave = tid >> 6;
  const int q = lane & 15, g = lane >> 4;
  const int wr = wave >> 1, wc = wave & 1;
  const int mblk = blockIdx.x * 128, nblk = blockIdx.y * 128;

  f32x4 acc[4][4];
  {
    f32x4 z = {0.f, 0.f, 0.f, 0.f};
#pragma unroll
    for (int i = 0; i < 4; ++i)
#pragma unroll
      for (int j = 0; j < 4; ++j) acc[i][j] = z;
  }

  const int r0 = tid >> 2;            // staging row
  const int e0 = (tid & 3) * 8;       // staging element offset within row
  for (int k0 = 0; k0 < 1024; k0 += 32) {
#pragma unroll
    for (int it = 0; it < 2; ++it) {
      const int row = r0 + it * 64;
      *(s16x8*)&As[row * 32 + e0] = *(const s16x8*)(A + (size_t)(mblk + row) * 1024 + k0 + e0);
      *(s16x8*)&Bs[row * 32 + e0] = *(const s16x8*)(W + (size_t)(nblk + row) * 1024 + k0 + e0);
    }
    __syncthreads();
    s16x8 af[4], bf[4];
#pragma unroll
    for (int t = 0; t < 4; ++t) {
      af[t] = *(const s16x8*)&As[(wr * 64 + t * 16 + q) * 32 + g * 8];
      bf[t] = *(const s16x8*)&Bs[(wc * 64 + t * 16 + q) * 32 + g * 8];
    }
#pragma unroll
    for (int mt = 0; mt < 4; ++mt)
#pragma unroll
      for (int nt = 0; nt < 4; ++nt)
        acc[mt][nt] = MFMA_B16(af[mt], bf[nt], acc[mt][nt]);
    __syncthreads();
  }

  // epilogue: C layout col = lane&15 (N), row = (lane>>4)*4 + j (M)
  if (mode == 3) {
    float* O = (float*)outp;
#pragma unroll
    for (int mt = 0; mt < 4; ++mt)
#pragma unroll
      for (int nt = 0; nt < 4; ++nt)
#pragma unroll
        for (int j = 0; j < 4; ++j) {
          const int s = mblk + wr * 64 + mt * 16 + g * 4 + j;
          const int o = nblk + wc * 64 + nt * 16 + q;
          O[(size_t)s * DD + o] = acc[mt][nt][j];
        }
  } else if (mode == 2) {
    ushort* Vt = (ushort*)outp;
#pragma unroll
    for (int mt = 0; mt < 4; ++mt)
#pragma unroll
      for (int nt = 0; nt < 4; ++nt) {
        const int s0 = mblk + wr * 64 + mt * 16 + g * 4;
        const int o  = nblk + wc * 64 + nt * 16 + q;
        const int h = o >> 6, dk = o & 63;
        const int b = s0 >> 11, sr = s0 & 2047;
        ushort4 pk;
        pk.x = f2bf(acc[mt][nt][0]); pk.y = f2bf(acc[mt][nt][1]);
        pk.z = f2bf(acc[mt][nt][2]); pk.w = f2bf(acc[mt][nt][3]);
        *(ushort4*)(Vt + ((size_t)((b * 16 + h) * 64 + dk)) * SS + sr) = pk;
      }
  } else {
    // Q/K proj: LDS-staged epilogue -> full-row contiguous 16B/lane stores.
    const float scale = (mode == 0) ? 0.125f : 1.0f;
    ushort* P = (ushort*)outp;
    ushort* wl = As + wave * 1024;   // 2KB wave-private staging (reuse As)
    const int h0 = (nblk + wc * 64) >> 6;
#pragma unroll
    for (int mt = 0; mt < 4; ++mt) {
      const int s0 = mblk + wr * 64 + mt * 16;
      const int b  = s0 >> 11, sr0 = s0 & 2047;
#pragma unroll
      for (int nt = 0; nt < 4; ++nt)
#pragma unroll
        for (int j = 0; j < 4; ++j)
          wl[(g * 4 + j) * 64 + nt * 16 + q] = f2bf(acc[mt][nt][j] * scale);
      // same-wave LDS write->read: compiler inserts lgkmcnt wait
#pragma unroll
      for (int it = 0; it < 2; ++it) {
        s16x8 v = *(const s16x8*)((char*)wl + it * 1024 + lane * 16);
        const int lr = it * 8 + (lane >> 3);
        const int c  = (lane & 7) * 8;
        *(s16x8*)(P + ((size_t)((b * 16 + h0) * SS) + sr0 + lr) * DKK + c) = v;
      }
    }
  }
}

// ---------------- pass 1: rden[b][q][k] = 1/sum_h exp(s[b,h,q,k]) ----------------
// grid (8 kg, 128 qb, 2 b), 256 thr = 4 waves.  Block stages Q[16h][16q][64]
// (72-padded rows) once; wave w owns 4 consecutive 16-key tiles (64 contiguous
// keys) and loops all 16 heads per tile.  Flattened (tile x head) loop with
// distance-1 K prefetch (named cur/next regs -> compiler keeps loads in
// flight; R6's unpipelined loop serialized at VGPR=36).  rden staged in LDS,
// stored as full 128B row-segments (R6's 8B scatter caused RFO amplification).
__global__ __launch_bounds__(256, 2) void den_kernel(
    const ushort* __restrict__ Qp, const ushort* __restrict__ Kp,
    ushort* __restrict__ Rden)
{
  __shared__ ushort Qs[16 * 16 * 72];   // [h][q][72 padded] = 36 KB
  __shared__ ushort rs[4][16 * 72];     // per-wave rden staging, 16 rows x 64(+8 pad)
  const int tid  = threadIdx.x;
  const int lane = tid & 63, w = tid >> 6;
  const int q = lane & 15, g = lane >> 4;
  const int kg = blockIdx.x, qb = blockIdx.y, b = blockIdx.z;
  const int qrow = qb * 16;
  const int kb64 = kg * 256 + w * 64;   // wave's 64 contiguous keys

  // stage Q tile: thread t copies row (h = t>>4, qq = t&15)
  {
    const int h = tid >> 4, qq = tid & 15;
    const ushort* src = Qp + ((size_t)(b * 16 + h) * SS + qrow + qq) * DKK;
    ushort* dst = Qs + (h * 16 + qq) * 72;
#pragma unroll
    for (int j = 0; j < 8; ++j)
      *(s16x8*)(dst + j * 8) = *(const s16x8*)(src + j * 8);
  }
  __syncthreads();

  // K fragment address for flattened iter it: h = it&15, j4 = it>>4
  const ushort* Kbase = Kp + (size_t)(b * 16) * SS * DKK + (size_t)q * DKK + g * 8;
  auto kaddr = [&](int it) -> const ushort* {
    const int h = it & 15, j4 = it >> 4;
    return Kbase + ((size_t)h * SS + (size_t)(kb64 + j4 * 16)) * DKK;
  };

  s16x8 kc0, kc1, kn0, kn1;
  {
    const ushort* Kb = kaddr(0);
    kc0 = *(const s16x8*)(Kb);
    kc1 = *(const s16x8*)(Kb + 32);
  }
  f32x4 den = {0.f, 0.f, 0.f, 0.f};
  ushort* rw = rs[w];

  for (int it = 0; it < 64; ++it) {
    // prefetch next (wraps harmlessly at the end)
    const ushort* Kn = kaddr((it + 1) & 63);
    kn0 = *(const s16x8*)(Kn);
    kn1 = *(const s16x8*)(Kn + 32);
    const int h = it & 15;
    const ushort* Qr = Qs + (h * 16 + q) * 72 + g * 8;
    s16x8 qf0 = *(const s16x8*)(Qr);
    s16x8 qf1 = *(const s16x8*)(Qr + 32);
    f32x4 c = {0.f, 0.f, 0.f, 0.f};
    c = MFMA_B16(kc0, qf0, c);
    c = MFMA_B16(kc1, qf1, c);
#pragma unroll
    for (int r = 0; r < 4; ++r) den[r] += __expf(c[r]);
    if ((it & 15) == 15) {
      const int j4 = it >> 4;
      ushort4 pk;
      pk.x = f2bf(1.0f / den[0]); pk.y = f2bf(1.0f / den[1]);
      pk.z = f2bf(1.0f / den[2]); pk.w = f2bf(1.0f / den[3]);
      *(ushort4*)(rw + q * 72 + j4 * 16 + g * 4) = pk;
      den[0] = den[1] = den[2] = den[3] = 0.f;
    }
    kc0 = kn0; kc1 = kn1;
  }

  // store staged rden: 2 passes x (8 rows x 128B contiguous), 16B/lane
  ushort* R = Rden + (size_t)b * SS * SS + (size_t)qrow * SS + kb64;
#pragma unroll
  for (int it = 0; it < 2; ++it) {
    const int row = it * 8 + (lane >> 3);
    const int seg = (lane & 7) * 8;
    s16x8 v = *(const s16x8*)(rw + row * 72 + seg);
    *(s16x8*)(R + (size_t)row * SS + seg) = v;
  }
}

// ---------------- pass 2: per-head attention, barrier-free, pipelined ----------------
// grid 1024 x 256 thr = 4096 independent waves.  bid&31 = bh (b = bh&1,
// h = bh>>1) -> bid%8 pins 4 (b,h) pairs (2 MB K/V) per XCD L2.  Wave owns
// (b, h, 16-q tile), sweeps 2048 keys in 64 32-key phases.  Distance-1
// prefetch of next phase's K fragments + rden words (named cur/next regs) so
// loads stay in flight under cur phase's MFMA+exp+PV (R5 lesson: hipcc does
// not pipeline these loops on its own; R6's VGPR=36 loop was serial).
__global__ __launch_bounds__(256, 2) void attn2_kernel(
    const ushort* __restrict__ Qp, const ushort* __restrict__ Kp,
    const ushort* __restrict__ Vt, const ushort* __restrict__ Rden,
    ushort* __restrict__ Ctx)
{
  __shared__ ushort aw_all[4][1024];   // 2 KB per wave

  const int tid  = threadIdx.x;
  const int lane = tid & 63;
  const int w    = tid >> 6;
  const int q    = lane & 15;
  const int g    = lane >> 4;
  const int bid  = blockIdx.x;
  const int bh   = bid & 31;
  const int b    = bh & 1, h = bh >> 1;
  const int qt   = (bid >> 5) * 4 + w;   // 0..127
  const int qrow = qt * 16;

  // Q fragments (B-operand: col=lane&15 -> q-row, dk contiguous per g)
  const ushort* Qb = Qp + ((size_t)(b * 16 + h) * SS + qrow + q) * DKK + g * 8;
  s16x8 qf0 = *(const s16x8*)(Qb);
  s16x8 qf1 = *(const s16x8*)(Qb + 32);

  const ushort* K0 = Kp + ((size_t)(b * 16 + h) * SS + q) * DKK + g * 8;
  const ushort* V0 = Vt + ((size_t)(b * 16 + h) * DKK + q) * SS + g * 8;
  const ushort* R0 = Rden + (size_t)b * SS * SS + (size_t)(qrow + q) * SS;

  f32x4 acc[4];
  {
    f32x4 z = {0.f, 0.f, 0.f, 0.f};
#pragma unroll
    for (int n = 0; n < 4; ++n) acc[n] = z;
  }

  char* aw = (char*)aw_all[w];
  const int swz = (q & 3) << 4;

  // prefetch phase 0: K fragments for both 16-key subtiles + rden
  s16x8 kA0, kA1, kB0, kB1;
  ushort4 rdA, rdB;
  {
    kA0 = *(const s16x8*)(K0);
    kA1 = *(const s16x8*)(K0 + 32);
    kB0 = *(const s16x8*)(K0 + 16 * DKK);
    kB1 = *(const s16x8*)(K0 + 16 * DKK + 32);
    rdA = *(const ushort4*)(R0 + g * 4);
    rdB = *(const ushort4*)(R0 + 16 + g * 4);
  }

  for (int kt = 0; kt < 64; ++kt) {
    const int base = kt * 32;
    // issue next phase's loads (wraps to 0 at the end, harmless reload)
    const int nbase = (kt < 63) ? base + 32 : 0;
    const ushort* KnA = K0 + (size_t)nbase * DKK;
    const ushort* KnB = K0 + (size_t)(nbase + 16) * DKK;
    s16x8 nA0 = *(const s16x8*)(KnA);
    s16x8 nA1 = *(const s16x8*)(KnA + 32);
    s16x8 nB0 = *(const s16x8*)(KnB);
    s16x8 nB1 = *(const s16x8*)(KnB + 32);
    ushort4 nrA = *(const ushort4*)(R0 + nbase + g * 4);
    ushort4 nrB = *(const ushort4*)(R0 + nbase + 16 + g * 4);
    // scores (swapped: c[r] = s[key=base(+16)+g*4+r][query=qrow+q])
    f32x4 cA = {0.f, 0.f, 0.f, 0.f}, cB = {0.f, 0.f, 0.f, 0.f};
    cA = MFMA_B16(kA0, qf0, cA);
    cA = MFMA_B16(kA1, qf1, cA);
    cB = MFMA_B16(kB0, qf0, cB);
    cB = MFMA_B16(kB1, qf1, cB);
    // attn = exp(s) * rden
    float aA[4], aB[4];
#pragma unroll
    for (int r = 0; r < 4; ++r) {
      aA[r] = __expf(cA[r]) * bf2f(((const ushort*)&rdA)[r]);
      aB[r] = __expf(cB[r]) * bf2f(((const ushort*)&rdB)[r]);
    }
    // bf16 re-layout via wave-private LDS (swizzled within 64B q-row)
    uint2 pA, pB;
    pA.x = (uint)f2bf(aA[0]) | ((uint)f2bf(aA[1]) << 16);
    pA.y = (uint)f2bf(aA[2]) | ((uint)f2bf(aA[3]) << 16);
    pB.x = (uint)f2bf(aB[0]) | ((uint)f2bf(aB[1]) << 16);
    pB.y = (uint)f2bf(aB[2]) | ((uint)f2bf(aB[3]) << 16);
    const int rowoff = q * 64;
    *(uint2*)(aw + rowoff + ((g * 8) ^ swz))      = pA;
    *(uint2*)(aw + rowoff + ((32 + g * 8) ^ swz)) = pB;
    // PV: A = attn row q (keys g*8..g*8+7 per lane), B = V^T rows
    s16x8 pa = *(const s16x8*)(aw + rowoff + ((g * 16) ^ swz));
#pragma unroll
    for (int n = 0; n < 4; ++n)
      acc[n] = MFMA_B16(pa, *(const s16x8*)(V0 + (size_t)(n * 16) * SS + base), acc[n]);
    // rotate prefetched registers
    kA0 = nA0; kA1 = nA1; kB0 = nB0; kB1 = nB1;
    rdA = nrA; rdB = nrB;
  }

  // epilogue: stage 16 rows x 64 cols (one head) in LDS, then coalesced
  // 16B/lane stores (each instr: 8 rows x 128B contiguous).
  ushort* aw16 = (ushort*)aw;
#pragma unroll
  for (int n = 0; n < 4; ++n)
#pragma unroll
    for (int j = 0; j < 4; ++j)
      aw16[(g * 4 + j) * 64 + n * 16 + q] = f2bf(acc[n][j]);
  ushort* P = Ctx + ((size_t)(b * SS) + qrow) * DD + h * 64;
#pragma unroll
  for (int it = 0; it < 2; ++it) {
    s16x8 v = *(const s16x8*)(aw + it * 1024 + lane * 16);
    const int lr = it * 8 + (lane >> 3);
    const int c  = (lane & 7) * 8;
    *(s16x8*)(P + (size_t)lr * DD + c) = v;
  }
}

extern "C" void kernel_launch(void* const* d_in, const int* in_sizes, int n_in,
                              void* d_out, int out_size, void* d_ws, size_t ws_size,
                              hipStream_t stream) {
  const float* Query = (const float*)d_in[0];
  const float* Key   = (const float*)d_in[1];
  const float* Value = (const float*)d_in[2];
  const float* Wq    = (const float*)d_in[3];
  const float* Wk    = (const float*)d_in[4];
  const float* Wv    = (const float*)d_in[5];
  const float* Wo    = (const float*)d_in[6];

  size_t off = 0;
  char* ws = (char*)d_ws;
  auto alloc = [&](size_t bytes) -> void* {
    void* p = ws + off;
    off += (bytes + 255) & ~(size_t)255;
    return p;
  };
  const size_t nX = (size_t)MM * DD;   // 4194304
  const size_t nW = (size_t)DD * DD;   // 1048576
  const size_t nS = (size_t)BB * SS * SS;  // 8388608
  ushort* Xq  = (ushort*)alloc(nX * 2);
  ushort* Xk  = (ushort*)alloc(nX * 2);
  ushort* Xv  = (ushort*)alloc(nX * 2);
  ushort* Wqb = (ushort*)alloc(nW * 2);
  ushort* Wkb = (ushort*)alloc(nW * 2);
  ushort* Wvb = (ushort*)alloc(nW * 2);
  ushort* Wob = (ushort*)alloc(nW * 2);
  ushort* Qp  = (ushort*)alloc(nX * 2);
  ushort* Kp  = (ushort*)alloc(nX * 2);
  ushort* Vtb = (ushort*)alloc(nX * 2);
  ushort* Rden = (ushort*)alloc(nS * 2);   // bf16 1/den, 16.7 MB
  ushort* Ctx = (ushort*)alloc(nX * 2);

  cvt_kernel<<<(int)(nX / 2048), 256, 0, stream>>>(Query, Xq, (int)nX);
  cvt_kernel<<<(int)(nX / 2048), 256, 0, stream>>>(Key,   Xk, (int)nX);
  cvt_kernel<<<(int)(nX / 2048), 256, 0, stream>>>(Value, Xv, (int)nX);
  cvt_kernel<<<(int)(nW / 2048), 256, 0, stream>>>(Wq, Wqb, (int)nW);
  cvt_kernel<<<(int)(nW / 2048), 256, 0, stream>>>(Wk, Wkb, (int)nW);
  cvt_kernel<<<(int)(nW / 2048), 256, 0, stream>>>(Wv, Wvb, (int)nW);
  cvt_kernel<<<(int)(nW / 2048), 256, 0, stream>>>(Wo, Wob, (int)nW);

  dim3 pg(32, 8), pb(256);
  proj_gemm<<<pg, pb, 0, stream>>>(Xq, Wqb, Qp, 0);
  proj_gemm<<<pg, pb, 0, stream>>>(Xk, Wkb, Kp, 1);
  proj_gemm<<<pg, pb, 0, stream>>>(Xv, Wvb, Vtb, 2);

  den_kernel<<<dim3(8, 128, 2), 256, 0, stream>>>(Qp, Kp, Rden);
  attn2_kernel<<<1024, 256, 0, stream>>>(Qp, Kp, Vtb, Rden, Ctx);

  proj_gemm<<<pg, pb, 0, stream>>>(Ctx, Wob, d_out, 3);
}

// Round 8
// 446.360 us; speedup vs baseline: 1.2171x; 1.2171x over previous
//
#include <hip/hip_runtime.h>
#include <stdint.h>

#define BB   2
#define SS   2048
#define DD   1024
#define HH   16
#define DKK  64
#define MM   (BB*SS)   // 4096 rows total

typedef __attribute__((ext_vector_type(4))) float f32x4;
typedef __attribute__((ext_vector_type(8))) short s16x8;

#define MFMA_B16(a, b, c) __builtin_amdgcn_mfma_f32_16x16x32_bf16((a), (b), (c), 0, 0, 0)

__device__ __forceinline__ ushort f2bf(float f) {
  uint u = __float_as_uint(f);
  u += 0x7FFFu + ((u >> 16) & 1u);   // round-to-nearest-even
  return (ushort)(u >> 16);
}
__device__ __forceinline__ float bf2f(ushort u) {
  return __uint_as_float((uint)u << 16);
}

// ---------------- fp32 -> bf16 convert (8 elems/thread) ----------------
__global__ void cvt_kernel(const float* __restrict__ src, ushort* __restrict__ dst, int n) {
  int i = (blockIdx.x * 256 + threadIdx.x) * 8;
  if (i >= n) return;
  const float4* s4 = (const float4*)(src + i);
  float4 a = s4[0], b = s4[1];
  union { ushort u[8]; s16x8 v; } r;
  r.u[0] = f2bf(a.x); r.u[1] = f2bf(a.y); r.u[2] = f2bf(a.z); r.u[3] = f2bf(a.w);
  r.u[4] = f2bf(b.x); r.u[5] = f2bf(b.y); r.u[6] = f2bf(b.z); r.u[7] = f2bf(b.w);
  *(s16x8*)(dst + i) = r.v;
}

// ---------------- combine 2 bf16 split-K partials -> bf16 ----------------
__global__ void combine2_kernel(const ushort* __restrict__ p, ushort* __restrict__ dst, int n) {
  int i = (blockIdx.x * 256 + threadIdx.x) * 8;
  if (i >= n) return;
  union { ushort u[8]; s16x8 v; } a, b, r;
  a.v = *(const s16x8*)(p + i);
  b.v = *(const s16x8*)(p + (size_t)n + i);
#pragma unroll
  for (int j = 0; j < 8; ++j)
    r.u[j] = f2bf(bf2f(a.u[j]) + bf2f(b.u[j]));
  *(s16x8*)(dst + i) = r.v;
}

// ---------------- Y = A @ W^T  (A:[4096,1024] bf16, W:[1024,1024] bf16) ----------------
// mode 0: Q-proj -> [B,H,S,DK] bf16, scaled by 1/8
// mode 1: K-proj -> [B,H,S,DK] bf16
// mode 2: V-proj -> [B,H,DK,S] bf16 (transposed)
// mode 3: O-proj -> [4096,1024] fp32 (d_out)
__global__ __launch_bounds__(256, 2) void proj_gemm(
    const ushort* __restrict__ A, const ushort* __restrict__ W,
    void* __restrict__ outp, int mode)
{
  __shared__ ushort As[128 * 32];
  __shared__ ushort Bs[128 * 32];
  const int tid  = threadIdx.x;
  const int lane = tid & 63, wave = tid >> 6;
  const int q = lane & 15, g = lane >> 4;
  const int wr = wave >> 1, wc = wave & 1;
  const int mblk = blockIdx.x * 128, nblk = blockIdx.y * 128;

  f32x4 acc[4][4];
  {
    f32x4 z = {0.f, 0.f, 0.f, 0.f};
#pragma unroll
    for (int i = 0; i < 4; ++i)
#pragma unroll
      for (int j = 0; j < 4; ++j) acc[i][j] = z;
  }

  const int r0 = tid >> 2;            // staging row
  const int e0 = (tid & 3) * 8;       // staging element offset within row
  for (int k0 = 0; k0 < 1024; k0 += 32) {
#pragma unroll
    for (int it = 0; it < 2; ++it) {
      const int row = r0 + it * 64;
      *(s16x8*)&As[row * 32 + e0] = *(const s16x8*)(A + (size_t)(mblk + row) * 1024 + k0 + e0);
      *(s16x8*)&Bs[row * 32 + e0] = *(const s16x8*)(W + (size_t)(nblk + row) * 1024 + k0 + e0);
    }
    __syncthreads();
    s16x8 af[4], bf[4];
#pragma unroll
    for (int t = 0; t < 4; ++t) {
      af[t] = *(const s16x8*)&As[(wr * 64 + t * 16 + q) * 32 + g * 8];
      bf[t] = *(const s16x8*)&Bs[(wc * 64 + t * 16 + q) * 32 + g * 8];
    }
#pragma unroll
    for (int mt = 0; mt < 4; ++mt)
#pragma unroll
      for (int nt = 0; nt < 4; ++nt)
        acc[mt][nt] = MFMA_B16(af[mt], bf[nt], acc[mt][nt]);
    __syncthreads();
  }

  // epilogue: C layout col = lane&15 (N), row = (lane>>4)*4 + j (M)
  if (mode == 3) {
    float* O = (float*)outp;
#pragma unroll
    for (int mt = 0; mt < 4; ++mt)
#pragma unroll
      for (int nt = 0; nt < 4; ++nt)
#pragma unroll
        for (int j = 0; j < 4; ++j) {
          const int s = mblk + wr * 64 + mt * 16 + g * 4 + j;
          const int o = nblk + wc * 64 + nt * 16 + q;
          O[(size_t)s * DD + o] = acc[mt][nt][j];
        }
  } else if (mode == 2) {
    ushort* Vt = (ushort*)outp;
#pragma unroll
    for (int mt = 0; mt < 4; ++mt)
#pragma unroll
      for (int nt = 0; nt < 4; ++nt) {
        const int s0 = mblk + wr * 64 + mt * 16 + g * 4;
        const int o  = nblk + wc * 64 + nt * 16 + q;
        const int h = o >> 6, dk = o & 63;
        const int b = s0 >> 11, sr = s0 & 2047;
        ushort4 pk;
        pk.x = f2bf(acc[mt][nt][0]); pk.y = f2bf(acc[mt][nt][1]);
        pk.z = f2bf(acc[mt][nt][2]); pk.w = f2bf(acc[mt][nt][3]);
        *(ushort4*)(Vt + ((size_t)((b * 16 + h) * 64 + dk)) * SS + sr) = pk;
      }
  } else {
    // Q/K proj: LDS-staged epilogue -> full-row contiguous 16B/lane stores.
    const float scale = (mode == 0) ? 0.125f : 1.0f;
    ushort* P = (ushort*)outp;
    ushort* wl = As + wave * 1024;   // 2KB wave-private staging (reuse As)
    const int h0 = (nblk + wc * 64) >> 6;
#pragma unroll
    for (int mt = 0; mt < 4; ++mt) {
      const int s0 = mblk + wr * 64 + mt * 16;
      const int b  = s0 >> 11, sr0 = s0 & 2047;
#pragma unroll
      for (int nt = 0; nt < 4; ++nt)
#pragma unroll
        for (int j = 0; j < 4; ++j)
          wl[(g * 4 + j) * 64 + nt * 16 + q] = f2bf(acc[mt][nt][j] * scale);
      // same-wave LDS write->read: compiler inserts lgkmcnt wait
#pragma unroll
      for (int it = 0; it < 2; ++it) {
        s16x8 v = *(const s16x8*)((char*)wl + it * 1024 + lane * 16);
        const int lr = it * 8 + (lane >> 3);
        const int c  = (lane & 7) * 8;
        *(s16x8*)(P + ((size_t)((b * 16 + h0) * SS) + sr0 + lr) * DKK + c) = v;
      }
    }
  }
}

// ---------------- pass 1: rden[b][q][k] = 1/sum_h exp(s) — GEMM-shaped ----------------
// proj_gemm skeleton: block = 128k x 128q tile; loop (h, d-half) = 32 staged
// steps of As=K-tile[128][32], Bs=Q-tile[128][32]; swapped GEMM C[k][q] =
// K@Q^T per head (Q pre-scaled 1/8); den += exp(acc) in registers per head.
// Barriers give the compiler the canonical shape it schedules well (R5-R7
// lesson: barrier-free per-wave chains serialize).  Epilogue: 1/den bounced
// through XOR-swizzled LDS (transpose k-major -> q-major) -> coalesced 16B
// stores of rden[b][q][k].
__global__ __launch_bounds__(256, 2) void den_kernel(
    const ushort* __restrict__ Qp, const ushort* __restrict__ Kp,
    ushort* __restrict__ Rden)
{
  __shared__ ushort smem[16384];        // 32 KB: staging 16 KB / bounce 32 KB (reused)
  ushort* As = smem;                    // K-tile [128][32]
  ushort* Bs = smem + 4096;             // Q-tile [128][32]
  const int tid  = threadIdx.x;
  const int lane = tid & 63, wave = tid >> 6;
  const int q = lane & 15, g = lane >> 4;
  const int wr = wave >> 1, wc = wave & 1;
  const int kblk = blockIdx.x * 128, qblk = blockIdx.y * 128;
  const int b = blockIdx.z;

  f32x4 den[4][4];
  {
    f32x4 z = {0.f, 0.f, 0.f, 0.f};
#pragma unroll
    for (int i = 0; i < 4; ++i)
#pragma unroll
      for (int j = 0; j < 4; ++j) den[i][j] = z;
  }

  const int r0 = tid >> 2;
  const int e0 = (tid & 3) * 8;
  for (int h = 0; h < 16; ++h) {
    const ushort* Kh = Kp + ((size_t)(b * 16 + h) * SS + kblk) * DKK;
    const ushort* Qh = Qp + ((size_t)(b * 16 + h) * SS + qblk) * DKK;
    f32x4 acc[4][4];
    {
      f32x4 z = {0.f, 0.f, 0.f, 0.f};
#pragma unroll
      for (int i = 0; i < 4; ++i)
#pragma unroll
        for (int j = 0; j < 4; ++j) acc[i][j] = z;
    }
#pragma unroll
    for (int dh = 0; dh < 2; ++dh) {
      const int d0 = dh * 32;
#pragma unroll
      for (int it = 0; it < 2; ++it) {
        const int row = r0 + it * 64;
        *(s16x8*)&As[row * 32 + e0] = *(const s16x8*)(Kh + (size_t)row * DKK + d0 + e0);
        *(s16x8*)&Bs[row * 32 + e0] = *(const s16x8*)(Qh + (size_t)row * DKK + d0 + e0);
      }
      __syncthreads();
      s16x8 af[4], bf[4];
#pragma unroll
      for (int t = 0; t < 4; ++t) {
        af[t] = *(const s16x8*)&As[(wr * 64 + t * 16 + q) * 32 + g * 8];
        bf[t] = *(const s16x8*)&Bs[(wc * 64 + t * 16 + q) * 32 + g * 8];
      }
#pragma unroll
      for (int mt = 0; mt < 4; ++mt)
#pragma unroll
        for (int nt = 0; nt < 4; ++nt)
          acc[mt][nt] = MFMA_B16(af[mt], bf[nt], acc[mt][nt]);
      __syncthreads();
    }
#pragma unroll
    for (int mt = 0; mt < 4; ++mt)
#pragma unroll
      for (int nt = 0; nt < 4; ++nt)
#pragma unroll
        for (int r = 0; r < 4; ++r)
          den[mt][nt][r] += __expf(acc[mt][nt][r]);
  }

  // epilogue: transpose 64k x 64q wave tile -> rden[q][k] via swizzled LDS.
  // (last loop action was a barrier, so smem is free to overwrite)
  char* aw2 = (char*)smem + wave * 8192;   // 8 KB wave-private
#pragma unroll
  for (int mt = 0; mt < 4; ++mt)
#pragma unroll
    for (int nt = 0; nt < 4; ++nt) {
      const int ql = nt * 16 + q;           // q_local within wave tile
      ushort4 pk;
      pk.x = f2bf(1.0f / den[mt][nt][0]);
      pk.y = f2bf(1.0f / den[mt][nt][1]);
      pk.z = f2bf(1.0f / den[mt][nt][2]);
      pk.w = f2bf(1.0f / den[mt][nt][3]);   // k_local = mt*16+g*4 + 0..3
      *(ushort4*)(aw2 + ql * 128 + ((mt * 32 + g * 8) ^ ((ql & 7) << 4))) = pk;
    }
  // same-wave LDS write->read (lgkmcnt auto), then coalesced stores
#pragma unroll
  for (int it = 0; it < 8; ++it) {
    const int idx = it * 64 + lane;
    const int row = idx >> 3;               // q_local 0..63
    const int seg = idx & 7;                // 16B segment of k
    s16x8 v = *(const s16x8*)(aw2 + row * 128 + ((seg * 16) ^ ((row & 7) << 4)));
    *(s16x8*)(Rden + (size_t)b * SS * SS
              + (size_t)(qblk + wc * 64 + row) * SS
              + kblk + wr * 64 + seg * 8) = v;
  }
}

// ---------------- pass 2: per-head attention, split-K=2, pinned prefetch ----------------
// grid 2048 x 256 thr = 8192 waves (R7 was grid-limited at 4096).  bid&31 = bh,
// bit5 = sk (key half), bid>>6 -> q-tile group.  bid%8 pins 4 (b,h) K/V pairs
// (2 MB) per XCD L2.  Wave owns (b,h,16q,1024 keys): 32 32-key phases.
// Distance-1 prefetch pinned with sched_barrier(0) (R7: without a fence the
// scheduler sinks prefetch loads back to their uses; VGPR 48 proved it).
__global__ __launch_bounds__(256, 2) void attn2_kernel(
    const ushort* __restrict__ Qp, const ushort* __restrict__ Kp,
    const ushort* __restrict__ Vt, const ushort* __restrict__ Rden,
    ushort* __restrict__ Part)
{
  __shared__ ushort aw_all[4][1024];   // 2 KB per wave

  const int tid  = threadIdx.x;
  const int lane = tid & 63;
  const int w    = tid >> 6;
  const int q    = lane & 15;
  const int g    = lane >> 4;
  const int bid  = blockIdx.x;
  const int bh   = bid & 31;
  const int b    = bh & 1, h = bh >> 1;
  const int sk   = (bid >> 5) & 1;
  const int qt   = (bid >> 6) * 4 + w;   // 0..127
  const int qrow = qt * 16;
  const int k0   = sk * 1024;

  // Q fragments (B-operand: col=lane&15 -> q-row, dk contiguous per g)
  const ushort* Qb = Qp + ((size_t)(b * 16 + h) * SS + qrow + q) * DKK + g * 8;
  s16x8 qf0 = *(const s16x8*)(Qb);
  s16x8 qf1 = *(const s16x8*)(Qb + 32);

  const ushort* K0 = Kp + ((size_t)(b * 16 + h) * SS + k0 + q) * DKK + g * 8;
  const ushort* V0 = Vt + ((size_t)(b * 16 + h) * DKK + q) * SS + k0 + g * 8;
  const ushort* R0 = Rden + (size_t)b * SS * SS + (size_t)(qrow + q) * SS + k0;

  f32x4 acc[4];
  {
    f32x4 z = {0.f, 0.f, 0.f, 0.f};
#pragma unroll
    for (int n = 0; n < 4; ++n) acc[n] = z;
  }

  char* aw = (char*)aw_all[w];
  const int swz = (q & 3) << 4;

  // prefetch phase 0
  s16x8 kA0, kA1, kB0, kB1;
  ushort4 rdA, rdB;
  {
    kA0 = *(const s16x8*)(K0);
    kA1 = *(const s16x8*)(K0 + 32);
    kB0 = *(const s16x8*)(K0 + 16 * DKK);
    kB1 = *(const s16x8*)(K0 + 16 * DKK + 32);
    rdA = *(const ushort4*)(R0 + g * 4);
    rdB = *(const ushort4*)(R0 + 16 + g * 4);
  }

  for (int kt = 0; kt < 32; ++kt) {
    const int base = kt * 32;
    // issue next phase's loads, then pin them (sched_barrier stops sinking)
    const int nbase = (kt < 31) ? base + 32 : 0;
    const ushort* KnA = K0 + (size_t)nbase * DKK;
    const ushort* KnB = K0 + (size_t)(nbase + 16) * DKK;
    s16x8 nA0 = *(const s16x8*)(KnA);
    s16x8 nA1 = *(const s16x8*)(KnA + 32);
    s16x8 nB0 = *(const s16x8*)(KnB);
    s16x8 nB1 = *(const s16x8*)(KnB + 32);
    ushort4 nrA = *(const ushort4*)(R0 + nbase + g * 4);
    ushort4 nrB = *(const ushort4*)(R0 + nbase + 16 + g * 4);
    __builtin_amdgcn_sched_barrier(0);
    // scores (swapped: c[r] = s[key=base(+16)+g*4+r][query=qrow+q])
    f32x4 cA = {0.f, 0.f, 0.f, 0.f}, cB = {0.f, 0.f, 0.f, 0.f};
    cA = MFMA_B16(kA0, qf0, cA);
    cA = MFMA_B16(kA1, qf1, cA);
    cB = MFMA_B16(kB0, qf0, cB);
    cB = MFMA_B16(kB1, qf1, cB);
    // attn = exp(s) * rden
    float aA[4], aB[4];
#pragma unroll
    for (int r = 0; r < 4; ++r) {
      aA[r] = __expf(cA[r]) * bf2f(((const ushort*)&rdA)[r]);
      aB[r] = __expf(cB[r]) * bf2f(((const ushort*)&rdB)[r]);
    }
    // bf16 re-layout via wave-private LDS (swizzled within 64B q-row)
    uint2 pA, pB;
    pA.x = (uint)f2bf(aA[0]) | ((uint)f2bf(aA[1]) << 16);
    pA.y = (uint)f2bf(aA[2]) | ((uint)f2bf(aA[3]) << 16);
    pB.x = (uint)f2bf(aB[0]) | ((uint)f2bf(aB[1]) << 16);
    pB.y = (uint)f2bf(aB[2]) | ((uint)f2bf(aB[3]) << 16);
    const int rowoff = q * 64;
    *(uint2*)(aw + rowoff + ((g * 8) ^ swz))      = pA;
    *(uint2*)(aw + rowoff + ((32 + g * 8) ^ swz)) = pB;
    // PV: A = attn row q (keys g*8..g*8+7 per lane), B = V^T rows
    s16x8 pa = *(const s16x8*)(aw + rowoff + ((g * 16) ^ swz));
#pragma unroll
    for (int n = 0; n < 4; ++n)
      acc[n] = MFMA_B16(pa, *(const s16x8*)(V0 + (size_t)(n * 16) * SS + base), acc[n]);
    // rotate prefetched registers
    kA0 = nA0; kA1 = nA1; kB0 = nB0; kB1 = nB1;
    rdA = nrA; rdB = nrB;
  }

  // epilogue: stage 16 rows x 64 cols (one head) in LDS, then coalesced
  // 16B/lane stores (each instr: 8 rows x 128B contiguous).
  ushort* aw16 = (ushort*)aw;
#pragma unroll
  for (int n = 0; n < 4; ++n)
#pragma unroll
    for (int j = 0; j < 4; ++j)
      aw16[(g * 4 + j) * 64 + n * 16 + q] = f2bf(acc[n][j]);
  ushort* P = Part + (size_t)sk * MM * DD + ((size_t)(b * SS) + qrow) * DD + h * 64;
#pragma unroll
  for (int it = 0; it < 2; ++it) {
    s16x8 v = *(const s16x8*)(aw + it * 1024 + lane * 16);
    const int lr = it * 8 + (lane >> 3);
    const int c  = (lane & 7) * 8;
    *(s16x8*)(P + (size_t)lr * DD + c) = v;
  }
}

extern "C" void kernel_launch(void* const* d_in, const int* in_sizes, int n_in,
                              void* d_out, int out_size, void* d_ws, size_t ws_size,
                              hipStream_t stream) {
  const float* Query = (const float*)d_in[0];
  const float* Key   = (const float*)d_in[1];
  const float* Value = (const float*)d_in[2];
  const float* Wq    = (const float*)d_in[3];
  const float* Wk    = (const float*)d_in[4];
  const float* Wv    = (const float*)d_in[5];
  const float* Wo    = (const float*)d_in[6];

  size_t off = 0;
  char* ws = (char*)d_ws;
  auto alloc = [&](size_t bytes) -> void* {
    void* p = ws + off;
    off += (bytes + 255) & ~(size_t)255;
    return p;
  };
  const size_t nX = (size_t)MM * DD;   // 4194304
  const size_t nW = (size_t)DD * DD;   // 1048576
  const size_t nS = (size_t)BB * SS * SS;  // 8388608
  ushort* Xq  = (ushort*)alloc(nX * 2);
  ushort* Xk  = (ushort*)alloc(nX * 2);
  ushort* Xv  = (ushort*)alloc(nX * 2);
  ushort* Wqb = (ushort*)alloc(nW * 2);
  ushort* Wkb = (ushort*)alloc(nW * 2);
  ushort* Wvb = (ushort*)alloc(nW * 2);
  ushort* Wob = (ushort*)alloc(nW * 2);
  ushort* Qp  = (ushort*)alloc(nX * 2);
  ushort* Kp  = (ushort*)alloc(nX * 2);
  ushort* Vtb = (ushort*)alloc(nX * 2);
  ushort* Rden = (ushort*)alloc(nS * 2);     // bf16 1/den, 16.7 MB
  ushort* Part = (ushort*)alloc(2 * nX * 2); // 2 bf16 split-K partials
  ushort* Ctx = (ushort*)alloc(nX * 2);

  cvt_kernel<<<(int)(nX / 2048), 256, 0, stream>>>(Query, Xq, (int)nX);
  cvt_kernel<<<(int)(nX / 2048), 256, 0, stream>>>(Key,   Xk, (int)nX);
  cvt_kernel<<<(int)(nX / 2048), 256, 0, stream>>>(Value, Xv, (int)nX);
  cvt_kernel<<<(int)(nW / 2048), 256, 0, stream>>>(Wq, Wqb, (int)nW);
  cvt_kernel<<<(int)(nW / 2048), 256, 0, stream>>>(Wk, Wkb, (int)nW);
  cvt_kernel<<<(int)(nW / 2048), 256, 0, stream>>>(Wv, Wvb, (int)nW);
  cvt_kernel<<<(int)(nW / 2048), 256, 0, stream>>>(Wo, Wob, (int)nW);

  dim3 pg(32, 8), pb(256);
  proj_gemm<<<pg, pb, 0, stream>>>(Xq, Wqb, Qp, 0);
  proj_gemm<<<pg, pb, 0, stream>>>(Xk, Wkb, Kp, 1);
  proj_gemm<<<pg, pb, 0, stream>>>(Xv, Wvb, Vtb, 2);

  den_kernel<<<dim3(16, 16, 2), 256, 0, stream>>>(Qp, Kp, Rden);
  attn2_kernel<<<2048, 256, 0, stream>>>(Qp, Kp, Vtb, Rden, Part);

  combine2_kernel<<<(int)(nX / 2048), 256, 0, stream>>>(Part, Ctx, (int)nX);

  proj_gemm<<<pg, pb, 0, stream>>>(Ctx, Wob, d_out, 3);
}

// Round 9
// 280.422 us; speedup vs baseline: 1.9373x; 1.5917x over previous
//
#include <hip/hip_runtime.h>
#include <stdint.h>

#define BB   2
#define SS   2048
#define DD   1024
#define HH   16
#define DKK  64
#define MM   (BB*SS)   // 4096 rows total

typedef __attribute__((ext_vector_type(4))) float f32x4;
typedef __attribute__((ext_vector_type(8))) short s16x8;

#define MFMA_B16(a, b, c) __builtin_amdgcn_mfma_f32_16x16x32_bf16((a), (b), (c), 0, 0, 0)

__device__ __forceinline__ ushort f2bf(float f) {
  uint u = __float_as_uint(f);
  u += 0x7FFFu + ((u >> 16) & 1u);   // round-to-nearest-even
  return (ushort)(u >> 16);
}
__device__ __forceinline__ float bf2f(ushort u) {
  return __uint_as_float((uint)u << 16);
}

// ---------------- fp32 -> bf16 convert (8 elems/thread) ----------------
__global__ void cvt_kernel(const float* __restrict__ src, ushort* __restrict__ dst, int n) {
  int i = (blockIdx.x * 256 + threadIdx.x) * 8;
  if (i >= n) return;
  const float4* s4 = (const float4*)(src + i);
  float4 a = s4[0], b = s4[1];
  union { ushort u[8]; s16x8 v; } r;
  r.u[0] = f2bf(a.x); r.u[1] = f2bf(a.y); r.u[2] = f2bf(a.z); r.u[3] = f2bf(a.w);
  r.u[4] = f2bf(b.x); r.u[5] = f2bf(b.y); r.u[6] = f2bf(b.z); r.u[7] = f2bf(b.w);
  *(s16x8*)(dst + i) = r.v;
}

// ---------------- Y = A @ W^T  (A:[4096,1024] bf16, W:[1024,1024] bf16) ----------------
// mode 0: Q-proj -> [B,H,S,DK] bf16, scaled by 1/8
// mode 1: K-proj -> [B,H,S,DK] bf16
// mode 2: V-proj -> [B,H,DK,S] bf16 (transposed)
// mode 3: O-proj -> [4096,1024] fp32 (d_out)
__global__ __launch_bounds__(256, 2) void proj_gemm(
    const ushort* __restrict__ A, const ushort* __restrict__ W,
    void* __restrict__ outp, int mode)
{
  __shared__ ushort As[128 * 32];
  __shared__ ushort Bs[128 * 32];
  const int tid  = threadIdx.x;
  const int lane = tid & 63, wave = tid >> 6;
  const int q = lane & 15, g = lane >> 4;
  const int wr = wave >> 1, wc = wave & 1;
  const int mblk = blockIdx.x * 128, nblk = blockIdx.y * 128;

  f32x4 acc[4][4];
  {
    f32x4 z = {0.f, 0.f, 0.f, 0.f};
#pragma unroll
    for (int i = 0; i < 4; ++i)
#pragma unroll
      for (int j = 0; j < 4; ++j) acc[i][j] = z;
  }

  const int r0 = tid >> 2;            // staging row
  const int e0 = (tid & 3) * 8;       // staging element offset within row
  for (int k0 = 0; k0 < 1024; k0 += 32) {
#pragma unroll
    for (int it = 0; it < 2; ++it) {
      const int row = r0 + it * 64;
      *(s16x8*)&As[row * 32 + e0] = *(const s16x8*)(A + (size_t)(mblk + row) * 1024 + k0 + e0);
      *(s16x8*)&Bs[row * 32 + e0] = *(const s16x8*)(W + (size_t)(nblk + row) * 1024 + k0 + e0);
    }
    __syncthreads();
    s16x8 af[4], bf[4];
#pragma unroll
    for (int t = 0; t < 4; ++t) {
      af[t] = *(const s16x8*)&As[(wr * 64 + t * 16 + q) * 32 + g * 8];
      bf[t] = *(const s16x8*)&Bs[(wc * 64 + t * 16 + q) * 32 + g * 8];
    }
#pragma unroll
    for (int mt = 0; mt < 4; ++mt)
#pragma unroll
      for (int nt = 0; nt < 4; ++nt)
        acc[mt][nt] = MFMA_B16(af[mt], bf[nt], acc[mt][nt]);
    __syncthreads();
  }

  // epilogue: C layout col = lane&15 (N), row = (lane>>4)*4 + j (M)
  if (mode == 3) {
    float* O = (float*)outp;
#pragma unroll
    for (int mt = 0; mt < 4; ++mt)
#pragma unroll
      for (int nt = 0; nt < 4; ++nt)
#pragma unroll
        for (int j = 0; j < 4; ++j) {
          const int s = mblk + wr * 64 + mt * 16 + g * 4 + j;
          const int o = nblk + wc * 64 + nt * 16 + q;
          O[(size_t)s * DD + o] = acc[mt][nt][j];
        }
  } else if (mode == 2) {
    ushort* Vt = (ushort*)outp;
#pragma unroll
    for (int mt = 0; mt < 4; ++mt)
#pragma unroll
      for (int nt = 0; nt < 4; ++nt) {
        const int s0 = mblk + wr * 64 + mt * 16 + g * 4;
        const int o  = nblk + wc * 64 + nt * 16 + q;
        const int h = o >> 6, dk = o & 63;
        const int b = s0 >> 11, sr = s0 & 2047;
        ushort4 pk;
        pk.x = f2bf(acc[mt][nt][0]); pk.y = f2bf(acc[mt][nt][1]);
        pk.z = f2bf(acc[mt][nt][2]); pk.w = f2bf(acc[mt][nt][3]);
        *(ushort4*)(Vt + ((size_t)((b * 16 + h) * 64 + dk)) * SS + sr) = pk;
      }
  } else {
    // Q/K proj: LDS-staged epilogue -> full-row contiguous 16B/lane stores.
    const float scale = (mode == 0) ? 0.125f : 1.0f;
    ushort* P = (ushort*)outp;
    ushort* wl = As + wave * 1024;   // 2KB wave-private staging (reuse As)
    const int h0 = (nblk + wc * 64) >> 6;
#pragma unroll
    for (int mt = 0; mt < 4; ++mt) {
      const int s0 = mblk + wr * 64 + mt * 16;
      const int b  = s0 >> 11, sr0 = s0 & 2047;
#pragma unroll
      for (int nt = 0; nt < 4; ++nt)
#pragma unroll
        for (int j = 0; j < 4; ++j)
          wl[(g * 4 + j) * 64 + nt * 16 + q] = f2bf(acc[mt][nt][j] * scale);
      // same-wave LDS write->read: compiler inserts lgkmcnt wait
#pragma unroll
      for (int it = 0; it < 2; ++it) {
        s16x8 v = *(const s16x8*)((char*)wl + it * 1024 + lane * 16);
        const int lr = it * 8 + (lane >> 3);
        const int c  = (lane & 7) * 8;
        *(s16x8*)(P + ((size_t)((b * 16 + h0) * SS) + sr0 + lr) * DKK + c) = v;
      }
    }
  }
}

// ---------------- pass 1: rden[b][q][k] = 1/sum_h exp(s) — GEMM-shaped ----------------
__global__ __launch_bounds__(256, 2) void den_kernel(
    const ushort* __restrict__ Qp, const ushort* __restrict__ Kp,
    ushort* __restrict__ Rden)
{
  __shared__ ushort smem[16384];        // 32 KB: staging 16 KB / bounce 32 KB (reused)
  ushort* As = smem;                    // K-tile [128][32]
  ushort* Bs = smem + 4096;             // Q-tile [128][32]
  const int tid  = threadIdx.x;
  const int lane = tid & 63, wave = tid >> 6;
  const int q = lane & 15, g = lane >> 4;
  const int wr = wave >> 1, wc = wave & 1;
  const int kblk = blockIdx.x * 128, qblk = blockIdx.y * 128;
  const int b = blockIdx.z;

  f32x4 den[4][4];
  {
    f32x4 z = {0.f, 0.f, 0.f, 0.f};
#pragma unroll
    for (int i = 0; i < 4; ++i)
#pragma unroll
      for (int j = 0; j < 4; ++j) den[i][j] = z;
  }

  const int r0 = tid >> 2;
  const int e0 = (tid & 3) * 8;
  for (int h = 0; h < 16; ++h) {
    const ushort* Kh = Kp + ((size_t)(b * 16 + h) * SS + kblk) * DKK;
    const ushort* Qh = Qp + ((size_t)(b * 16 + h) * SS + qblk) * DKK;
    f32x4 acc[4][4];
    {
      f32x4 z = {0.f, 0.f, 0.f, 0.f};
#pragma unroll
      for (int i = 0; i < 4; ++i)
#pragma unroll
        for (int j = 0; j < 4; ++j) acc[i][j] = z;
    }
#pragma unroll
    for (int dh = 0; dh < 2; ++dh) {
      const int d0 = dh * 32;
#pragma unroll
      for (int it = 0; it < 2; ++it) {
        const int row = r0 + it * 64;
        *(s16x8*)&As[row * 32 + e0] = *(const s16x8*)(Kh + (size_t)row * DKK + d0 + e0);
        *(s16x8*)&Bs[row * 32 + e0] = *(const s16x8*)(Qh + (size_t)row * DKK + d0 + e0);
      }
      __syncthreads();
      s16x8 af[4], bf[4];
#pragma unroll
      for (int t = 0; t < 4; ++t) {
        af[t] = *(const s16x8*)&As[(wr * 64 + t * 16 + q) * 32 + g * 8];
        bf[t] = *(const s16x8*)&Bs[(wc * 64 + t * 16 + q) * 32 + g * 8];
      }
#pragma unroll
      for (int mt = 0; mt < 4; ++mt)
#pragma unroll
        for (int nt = 0; nt < 4; ++nt)
          acc[mt][nt] = MFMA_B16(af[mt], bf[nt], acc[mt][nt]);
      __syncthreads();
    }
#pragma unroll
    for (int mt = 0; mt < 4; ++mt)
#pragma unroll
      for (int nt = 0; nt < 4; ++nt)
#pragma unroll
        for (int r = 0; r < 4; ++r)
          den[mt][nt][r] += __expf(acc[mt][nt][r]);
  }

  // epilogue: transpose 64k x 64q wave tile -> rden[q][k] via swizzled LDS.
  char* aw2 = (char*)smem + wave * 8192;   // 8 KB wave-private
#pragma unroll
  for (int mt = 0; mt < 4; ++mt)
#pragma unroll
    for (int nt = 0; nt < 4; ++nt) {
      const int ql = nt * 16 + q;           // q_local within wave tile
      ushort4 pk;
      pk.x = f2bf(1.0f / den[mt][nt][0]);
      pk.y = f2bf(1.0f / den[mt][nt][1]);
      pk.z = f2bf(1.0f / den[mt][nt][2]);
      pk.w = f2bf(1.0f / den[mt][nt][3]);   // k_local = mt*16+g*4 + 0..3
      *(ushort4*)(aw2 + ql * 128 + ((mt * 32 + g * 8) ^ ((ql & 7) << 4))) = pk;
    }
  // same-wave LDS write->read (lgkmcnt auto), then coalesced stores
#pragma unroll
  for (int it = 0; it < 8; ++it) {
    const int idx = it * 64 + lane;
    const int row = idx >> 3;               // q_local 0..63
    const int seg = idx & 7;                // 16B segment of k
    s16x8 v = *(const s16x8*)(aw2 + row * 128 + ((seg * 16) ^ ((row & 7) << 4)));
    *(s16x8*)(Rden + (size_t)b * SS * SS
              + (size_t)(qblk + wc * 64 + row) * SS
              + kblk + wr * 64 + seg * 8) = v;
  }
}

// ---------------- pass 2: block-tiled attention (GEMM-shaped) ----------------
// grid 512: bid = qt*32 + bh, bh = b*16+h.  bid%8 = bh%8 pins 4 (b,h) pairs'
// K/V (1 MB) per XCD L2.  Block = (b, h, 128 q-rows); 4 waves, wave w owns
// q-rows w*32..+31 (2 subtiles of 16).  32 phases x 64 keys: stage K-tile
// [64][64] + V^T-tile [64][64] + rden-tile [128][64] in XOR-swizzled LDS
// (shared by all 4 waves -> 6x less L2 traffic than per-wave streaming, and
// no per-phase vmcnt(0) drain since MFMA operands come from LDS), barrier,
// QK->exp*rden->P(LDS)->PV, barrier.  No split-K: Ctx written directly.
__global__ __launch_bounds__(256, 2) void attn3_kernel(
    const ushort* __restrict__ Qp, const ushort* __restrict__ Kp,
    const ushort* __restrict__ Vt, const ushort* __restrict__ Rden,
    ushort* __restrict__ Ctx)
{
  __shared__ ushort Ktile[64 * 64];    //  8 KB, row k (swz by k&7)
  __shared__ ushort Vtile[64 * 64];    //  8 KB, row dk (swz by dk&7)
  __shared__ ushort Rtile[128 * 64];   // 16 KB, row q-local (swz by q&7)
  __shared__ ushort aw_all[4][2048];   // 16 KB, per-wave P / epilogue bounce

  const int tid  = threadIdx.x;
  const int lane = tid & 63;
  const int w    = tid >> 6;
  const int q    = lane & 15;
  const int g    = lane >> 4;
  const int bid  = blockIdx.x;
  const int bh   = bid & 31;
  const int b    = bh >> 4, h = bh & 15;
  const int qblk = (bid >> 5) * 128;

  // hoist Q fragments (B-operand: col=lane&15 -> q-row, dk contiguous per g)
  s16x8 qf[2][2];
#pragma unroll
  for (int qs = 0; qs < 2; ++qs) {
    const ushort* Qb = Qp + ((size_t)bh * SS + qblk + w * 32 + qs * 16 + q) * DKK + g * 8;
    qf[qs][0] = *(const s16x8*)(Qb);
    qf[qs][1] = *(const s16x8*)(Qb + 32);
  }

  const ushort* Ks = Kp + (size_t)bh * SS * DKK;        // K rows contiguous
  const ushort* Vs = Vt + (size_t)bh * DKK * SS;        // V^T rows stride SS
  const ushort* Rs = Rden + (size_t)b * SS * SS + (size_t)qblk * SS;

  f32x4 acc[2][4];
  {
    f32x4 z = {0.f, 0.f, 0.f, 0.f};
#pragma unroll
    for (int qs = 0; qs < 2; ++qs)
#pragma unroll
      for (int n = 0; n < 4; ++n) acc[qs][n] = z;
  }

  ushort* aw = aw_all[w];

  for (int kt = 0; kt < 32; ++kt) {
    const int k0 = kt * 64;
    // ---- stage K (8KB contiguous), V^T (64 rows x 128B), rden (128 rows x 128B)
#pragma unroll
    for (int it = 0; it < 2; ++it) {
      const int c = tid + it * 256;            // 0..511
      const int row = c >> 3, seg = c & 7;
      const int d = ((seg * 8) ^ ((row & 7) << 3));
      *(s16x8*)&Ktile[row * 64 + d] = *(const s16x8*)(Ks + (size_t)(k0) * DKK + c * 8);
      *(s16x8*)&Vtile[row * 64 + d] = *(const s16x8*)(Vs + (size_t)row * SS + k0 + seg * 8);
    }
#pragma unroll
    for (int it = 0; it < 4; ++it) {
      const int c = tid + it * 256;            // 0..1023
      const int row = c >> 3, seg = c & 7;
      *(s16x8*)&Rtile[row * 64 + ((seg * 8) ^ ((row & 7) << 3))] =
          *(const s16x8*)(Rs + (size_t)row * SS + k0 + seg * 8);
    }
    __syncthreads();

    // ---- QK scores -> exp * rden -> P into wave-private aw
#pragma unroll
    for (int qs = 0; qs < 2; ++qs) {
      const int qr = w * 32 + qs * 16 + q;     // q-local row in Rtile
      const int ar = qs * 16 + q;              // row in aw
#pragma unroll
      for (int ks = 0; ks < 4; ++ks) {
        const int kr = ks * 16 + q;
        s16x8 a0 = *(const s16x8*)&Ktile[kr * 64 + ((g * 8) ^ ((kr & 7) << 3))];
        s16x8 a1 = *(const s16x8*)&Ktile[kr * 64 + ((32 + g * 8) ^ ((kr & 7) << 3))];
        f32x4 c = {0.f, 0.f, 0.f, 0.f};
        c = MFMA_B16(a0, qf[qs][0], c);
        c = MFMA_B16(a1, qf[qs][1], c);
        // rden[qr][ks*16+g*4 + 0..3]
        const ushort* rp = &Rtile[qr * 64 + ((ks * 16 + g * 4) ^ ((qr & 7) << 3))];
        uint2 pp;
        pp.x = (uint)f2bf(__expf(c[0]) * bf2f(rp[0])) |
               ((uint)f2bf(__expf(c[1]) * bf2f(rp[1])) << 16);
        pp.y = (uint)f2bf(__expf(c[2]) * bf2f(rp[2])) |
               ((uint)f2bf(__expf(c[3]) * bf2f(rp[3])) << 16);
        *(uint2*)&aw[ar * 64 + ((ks * 16 + g * 4) ^ ((ar & 7) << 3))] = pp;
      }
    }
    // ---- PV over the 64-key tile (same-wave aw; lgkmcnt auto)
#pragma unroll
    for (int kc = 0; kc < 2; ++kc) {
      s16x8 vf[4];
#pragma unroll
      for (int n = 0; n < 4; ++n) {
        const int vr = n * 16 + q;
        vf[n] = *(const s16x8*)&Vtile[vr * 64 + ((kc * 32 + g * 8) ^ ((vr & 7) << 3))];
      }
#pragma unroll
      for (int qs = 0; qs < 2; ++qs) {
        const int ar = qs * 16 + q;
        s16x8 pa = *(const s16x8*)&aw[ar * 64 + ((kc * 32 + g * 8) ^ ((ar & 7) << 3))];
#pragma unroll
        for (int n = 0; n < 4; ++n)
          acc[qs][n] = MFMA_B16(pa, vf[n], acc[qs][n]);
      }
    }
    __syncthreads();
  }

  // epilogue: stage 32 rows x 64 cols in wave-private aw, then coalesced
  // 16B/lane stores (each instr: 8 rows x 128B contiguous).
#pragma unroll
  for (int qs = 0; qs < 2; ++qs)
#pragma unroll
    for (int n = 0; n < 4; ++n)
#pragma unroll
      for (int j = 0; j < 4; ++j)
        aw[(qs * 16 + g * 4 + j) * 64 + n * 16 + q] = f2bf(acc[qs][n][j]);
  ushort* P = Ctx + ((size_t)(b * SS) + qblk + w * 32) * DD + h * 64;
#pragma unroll
  for (int it = 0; it < 4; ++it) {
    const int idx = it * 64 + lane;
    const int row = idx >> 3;
    const int seg = idx & 7;
    s16x8 v = *(const s16x8*)&aw[row * 64 + seg * 8];
    *(s16x8*)(P + (size_t)row * DD + seg * 8) = v;
  }
}

extern "C" void kernel_launch(void* const* d_in, const int* in_sizes, int n_in,
                              void* d_out, int out_size, void* d_ws, size_t ws_size,
                              hipStream_t stream) {
  const float* Query = (const float*)d_in[0];
  const float* Key   = (const float*)d_in[1];
  const float* Value = (const float*)d_in[2];
  const float* Wq    = (const float*)d_in[3];
  const float* Wk    = (const float*)d_in[4];
  const float* Wv    = (const float*)d_in[5];
  const float* Wo    = (const float*)d_in[6];

  size_t off = 0;
  char* ws = (char*)d_ws;
  auto alloc = [&](size_t bytes) -> void* {
    void* p = ws + off;
    off += (bytes + 255) & ~(size_t)255;
    return p;
  };
  const size_t nX = (size_t)MM * DD;   // 4194304
  const size_t nW = (size_t)DD * DD;   // 1048576
  const size_t nS = (size_t)BB * SS * SS;  // 8388608
  ushort* Xq  = (ushort*)alloc(nX * 2);
  ushort* Xk  = (ushort*)alloc(nX * 2);
  ushort* Xv  = (ushort*)alloc(nX * 2);
  ushort* Wqb = (ushort*)alloc(nW * 2);
  ushort* Wkb = (ushort*)alloc(nW * 2);
  ushort* Wvb = (ushort*)alloc(nW * 2);
  ushort* Wob = (ushort*)alloc(nW * 2);
  ushort* Qp  = (ushort*)alloc(nX * 2);
  ushort* Kp  = (ushort*)alloc(nX * 2);
  ushort* Vtb = (ushort*)alloc(nX * 2);
  ushort* Rden = (ushort*)alloc(nS * 2);     // bf16 1/den, 16.7 MB
  ushort* Ctx = (ushort*)alloc(nX * 2);

  cvt_kernel<<<(int)(nX / 2048), 256, 0, stream>>>(Query, Xq, (int)nX);
  cvt_kernel<<<(int)(nX / 2048), 256, 0, stream>>>(Key,   Xk, (int)nX);
  cvt_kernel<<<(int)(nX / 2048), 256, 0, stream>>>(Value, Xv, (int)nX);
  cvt_kernel<<<(int)(nW / 2048), 256, 0, stream>>>(Wq, Wqb, (int)nW);
  cvt_kernel<<<(int)(nW / 2048), 256, 0, stream>>>(Wk, Wkb, (int)nW);
  cvt_kernel<<<(int)(nW / 2048), 256, 0, stream>>>(Wv, Wvb, (int)nW);
  cvt_kernel<<<(int)(nW / 2048), 256, 0, stream>>>(Wo, Wob, (int)nW);

  dim3 pg(32, 8), pb(256);
  proj_gemm<<<pg, pb, 0, stream>>>(Xq, Wqb, Qp, 0);
  proj_gemm<<<pg, pb, 0, stream>>>(Xk, Wkb, Kp, 1);
  proj_gemm<<<pg, pb, 0, stream>>>(Xv, Wvb, Vtb, 2);

  den_kernel<<<dim3(16, 16, 2), 256, 0, stream>>>(Qp, Kp, Rden);
  attn3_kernel<<<512, 256, 0, stream>>>(Qp, Kp, Vtb, Rden, Ctx);

  proj_gemm<<<pg, pb, 0, stream>>>(Ctx, Wob, d_out, 3);
}